// Round 1
// baseline (795.376 us; speedup 1.0000x reference)
//
#include <hip/hip_runtime.h>

typedef __bf16  bf16x8 __attribute__((ext_vector_type(8)));
typedef float   f32x16 __attribute__((ext_vector_type(16)));

__device__ __forceinline__ unsigned short f2bf(float f) {
    union { float f; unsigned int u; } v; v.f = f;
    unsigned int r = (v.u + 0x7fffu + ((v.u >> 16) & 1u)) >> 16;
    return (unsigned short)r;
}

// ---------------------------------------------------------------------------
// Kernel A (unchanged): weight transform U = G g G^T, bf16 in MFMA B-fragment
// order: Up[((ad*16 + cg)*256 + k)*8 + j]   where c = cg*8 + j
// ---------------------------------------------------------------------------
__global__ void wino_wtrans(const float* __restrict__ w, unsigned short* __restrict__ Up) {
    int k = blockIdx.x;        // 0..255
    int c = threadIdx.x;       // 0..127
    const float* g = w + (k * 128 + c) * 9;
    float g00=g[0],g01=g[1],g02=g[2],g10=g[3],g11=g[4],g12=g[5],g20=g[6],g21=g[7],g22=g[8];
    float T[4][3];
    T[0][0]=g00;                    T[0][1]=g01;                    T[0][2]=g02;
    T[1][0]=0.5f*(g00+g10+g20);     T[1][1]=0.5f*(g01+g11+g21);     T[1][2]=0.5f*(g02+g12+g22);
    T[2][0]=0.5f*(g00-g10+g20);     T[2][1]=0.5f*(g01-g11+g21);     T[2][2]=0.5f*(g02-g12+g22);
    T[3][0]=g20;                    T[3][1]=g21;                    T[3][2]=g22;
    int cg = c >> 3, j = c & 7;
    #pragma unroll
    for (int a = 0; a < 4; ++a) {
        float u0 = T[a][0];
        float u1 = 0.5f*(T[a][0]+T[a][1]+T[a][2]);
        float u2 = 0.5f*(T[a][0]-T[a][1]+T[a][2]);
        float u3 = T[a][2];
        float uu[4] = {u0,u1,u2,u3};
        #pragma unroll
        for (int d = 0; d < 4; ++d) {
            Up[(((size_t)((a*4+d)*16 + cg))*256 + k)*8 + j] = f2bf(uu[d]);
        }
    }
}

// ---------------------------------------------------------------------------
// Fused kernel: per block (row-pair bx, k-half by), loop c in chunks of 32:
//   stage: compute V = Bt d Bt^T for 64 n x 32 c into LDS (A-fragment order,
//          double buffered), reg-staged x with issue-early / write-late split.
//   mfma : 16 ad x 2 MFMA(32x32x16) per chunk, inverse transform folded
//          incrementally into 4 Y accumulators (At entries are 0/+-1).
// LDS: 2 x 64KB.  Block 512 thr (8 waves: 2 n-rows x 4 k-tiles of 32).
// ---------------------------------------------------------------------------
__global__ __launch_bounds__(512) void wino_fused(
        const float* __restrict__ x, const unsigned short* __restrict__ Up,
        const float* __restrict__ bias, float* __restrict__ out)
{
    __shared__ unsigned short Vs[2][16*4*64*8];   // [buf][ad][oct][n][j] bf16

    const bf16x8* U8 = (const bf16x8*)Up;
    const int t  = threadIdx.x;
    const int by = blockIdx.x;      // 0..1   k-split (fast axis -> L2 x-reuse)
    const int bx = blockIdx.y;      // 0..495 row-pair

    // ---- stage mapping: t = [cgb][rsel][qh][l4][jp] ----
    const int jp   = t & 3;          // c-pair within octet (4B LDS stride -> no bank conflict)
    const int l4   = (t >> 2) & 15;
    const int qh   = (t >> 6) & 1;
    const int rsel = (t >> 7) & 1;
    const int cgb  = (t >> 8) & 1;
    const int sq   = qh * 16 + l4;           // 0..31
    const int srow = bx * 2 + rsel;          // = b*31 + p
    const int sb   = srow / 31, sp = srow % 31;
    const int nloc_s = rsel * 32 + sq;
    const bool valid = (sq < 31);
    const float* xb = x + (((size_t)sb * 128) * 64 + 2 * sp) * 64 + 2 * sq;  // + c*4096

    // ---- mfma mapping ----
    const int lane = t & 63, wave = t >> 6;
    const int l31 = lane & 31, q2 = lane >> 5;
    const int wn = wave & 1, wk = wave >> 1;        // 2 n-rows x 4 k-tiles
    const int row = bx * 2 + wn;
    const int k0  = by * 128 + wk * 32;
    const int bOff = q2 * 256 + k0 + l31;
    const int aOff = wn * 32 + l31;

    f32x16 Y00, Y01, Y10, Y11;
    #pragma unroll
    for (int z = 0; z < 16; ++z) { Y00[z]=0.f; Y01[z]=0.f; Y10[z]=0.f; Y11[z]=0.f; }

    float2 xr[2][2][4][2];   // [slot u][ch][xrow i][col-pair] staged x (static idx only)

    auto stage_load = [&](int chunk) {
        #pragma unroll
        for (int u = 0; u < 2; ++u) {
            #pragma unroll
            for (int ch = 0; ch < 2; ++ch) {
                const int c = chunk*32 + (u*2 + cgb)*8 + jp*2 + ch;
                const float* p = xb + (size_t)c * 4096;
                #pragma unroll
                for (int i = 0; i < 4; ++i) {
                    if (valid) {
                        xr[u][ch][i][0] = *(const float2*)(p + i*64);
                        xr[u][ch][i][1] = *(const float2*)(p + i*64 + 2);
                    } else {
                        xr[u][ch][i][0] = make_float2(0.f, 0.f);
                        xr[u][ch][i][1] = make_float2(0.f, 0.f);
                    }
                }
            }
        }
    };

    auto stage_write = [&](int buf) {
        unsigned* dst = (unsigned*)Vs[buf];
        #pragma unroll
        for (int u = 0; u < 2; ++u) {
            float V2[2][4][4];
            #pragma unroll
            for (int ch = 0; ch < 2; ++ch) {
                float dd[4][4];
                #pragma unroll
                for (int i = 0; i < 4; ++i) {
                    dd[i][0] = xr[u][ch][i][0].x; dd[i][1] = xr[u][ch][i][0].y;
                    dd[i][2] = xr[u][ch][i][1].x; dd[i][3] = xr[u][ch][i][1].y;
                }
                float s[4][4];
                #pragma unroll
                for (int jj = 0; jj < 4; ++jj) {
                    s[0][jj] = dd[0][jj] - dd[2][jj];
                    s[1][jj] = dd[1][jj] + dd[2][jj];
                    s[2][jj] = dd[2][jj] - dd[1][jj];
                    s[3][jj] = dd[1][jj] - dd[3][jj];
                }
                #pragma unroll
                for (int a = 0; a < 4; ++a) {
                    V2[ch][a][0] = s[a][0] - s[a][2];
                    V2[ch][a][1] = s[a][1] + s[a][2];
                    V2[ch][a][2] = s[a][2] - s[a][1];
                    V2[ch][a][3] = s[a][1] - s[a][3];
                }
            }
            const int cg2  = u*2 + cgb;
            const int base = cg2*256 + nloc_s*4 + jp;
            #pragma unroll
            for (int a = 0; a < 4; ++a)
                #pragma unroll
                for (int d = 0; d < 4; ++d) {
                    unsigned lo = f2bf(V2[0][a][d]);
                    unsigned hi = f2bf(V2[1][a][d]);
                    dst[(a*4 + d)*1024 + base] = lo | (hi << 16);
                }
        }
    };

    // prologue: stage chunk 0
    stage_load(0);
    stage_write(0);
    __syncthreads();

    #pragma unroll
    for (int chunk = 0; chunk < 4; ++chunk) {
        const int cur = chunk & 1;
        if (chunk < 3) stage_load(chunk + 1);     // issue early: overlap with MFMA phase

        const bf16x8* va = (const bf16x8*)Vs[cur];
        #pragma unroll
        for (int ad = 0; ad < 16; ++ad) {
            f32x16 m;
            #pragma unroll
            for (int z = 0; z < 16; ++z) m[z] = 0.f;
            #pragma unroll
            for (int cb = 0; cb < 2; ++cb) {
                bf16x8 av = va[(ad*4 + cb*2 + q2)*64 + aOff];
                bf16x8 bv = U8[(size_t)(ad*16 + chunk*4 + cb*2)*256 + bOff];
                m = __builtin_amdgcn_mfma_f32_32x32x16_bf16(av, bv, m, 0, 0, 0);
            }
            const int a_i = ad >> 2, d_i = ad & 3;
            constexpr float A0[4] = {1.f, 1.f,  1.f,  0.f};
            constexpr float A1[4] = {0.f, 1.f, -1.f, -1.f};
            const float w00 = A0[a_i]*A0[d_i], w01 = A0[a_i]*A1[d_i];
            const float w10 = A1[a_i]*A0[d_i], w11 = A1[a_i]*A1[d_i];
            if (w00 != 0.f) Y00 += w00 * m;       // constant-folded -> add/sub
            if (w01 != 0.f) Y01 += w01 * m;
            if (w10 != 0.f) Y10 += w10 * m;
            if (w11 != 0.f) Y11 += w11 * m;
        }
        if (chunk < 3) stage_write(cur ^ 1);      // write late: waits x loads after MFMA
        __syncthreads();
    }

    // Epilogue: lane owns k-plane k0+l31; C/D row r -> q = (r&3)+8*(r>>2)+4*q2
    int b = row / 31, p = row % 31;
    int k = k0 + l31;
    float bvs = bias[k];
    float* op = out + (size_t)(b*256 + k) * 62 * 62;
    #pragma unroll
    for (int r = 0; r < 16; ++r) {
        int q = (r & 3) + 8*(r >> 2) + 4*q2;
        if (q < 31) {
            *(float2*)(op + (2*p+0)*62 + 2*q) = make_float2(Y00[r] + bvs, Y01[r] + bvs);
            *(float2*)(op + (2*p+1)*62 + 2*q) = make_float2(Y10[r] + bvs, Y11[r] + bvs);
        }
    }
}

// ---------------------------------------------------------------------------
extern "C" void kernel_launch(void* const* d_in, const int* in_sizes, int n_in,
                              void* d_out, int out_size, void* d_ws, size_t ws_size,
                              hipStream_t stream) {
    const float* x    = (const float*)d_in[0];
    const float* w    = (const float*)d_in[1];
    const float* bias = (const float*)d_in[2];
    float* out = (float*)d_out;

    unsigned short* Up = (unsigned short*)d_ws;   // 16*16*256*8 bf16 = 1 MB

    wino_wtrans<<<dim3(256),    dim3(128), 0, stream>>>(w, Up);
    wino_fused <<<dim3(2, 496), dim3(512), 0, stream>>>(x, Up, bias, out);
}

// Round 2
// 277.745 us; speedup vs baseline: 2.8637x; 2.8637x over previous
//
#include <hip/hip_runtime.h>

typedef __bf16  bf16x8 __attribute__((ext_vector_type(8)));
typedef float   f32x16 __attribute__((ext_vector_type(16)));

__device__ __forceinline__ unsigned short f2bf(float f) {
    union { float f; unsigned int u; } v; v.f = f;
    unsigned int r = (v.u + 0x7fffu + ((v.u >> 16) & 1u)) >> 16;
    return (unsigned short)r;
}

// ---------------------------------------------------------------------------
// Kernel A (unchanged): weight transform U = G g G^T, bf16 in MFMA B-fragment
// order: Up[((ad*16 + cg)*256 + k)*8 + j]   where c = cg*8 + j
// ---------------------------------------------------------------------------
__global__ void wino_wtrans(const float* __restrict__ w, unsigned short* __restrict__ Up) {
    int k = blockIdx.x;        // 0..255
    int c = threadIdx.x;       // 0..127
    const float* g = w + (k * 128 + c) * 9;
    float g00=g[0],g01=g[1],g02=g[2],g10=g[3],g11=g[4],g12=g[5],g20=g[6],g21=g[7],g22=g[8];
    float T[4][3];
    T[0][0]=g00;                    T[0][1]=g01;                    T[0][2]=g02;
    T[1][0]=0.5f*(g00+g10+g20);     T[1][1]=0.5f*(g01+g11+g21);     T[1][2]=0.5f*(g02+g12+g22);
    T[2][0]=0.5f*(g00-g10+g20);     T[2][1]=0.5f*(g01-g11+g21);     T[2][2]=0.5f*(g02-g12+g22);
    T[3][0]=g20;                    T[3][1]=g21;                    T[3][2]=g22;
    int cg = c >> 3, j = c & 7;
    #pragma unroll
    for (int a = 0; a < 4; ++a) {
        float u0 = T[a][0];
        float u1 = 0.5f*(T[a][0]+T[a][1]+T[a][2]);
        float u2 = 0.5f*(T[a][0]-T[a][1]+T[a][2]);
        float u3 = T[a][2];
        float uu[4] = {u0,u1,u2,u3};
        #pragma unroll
        for (int d = 0; d < 4; ++d) {
            Up[(((size_t)((a*4+d)*16 + cg))*256 + k)*8 + j] = f2bf(uu[d]);
        }
    }
}

// ---------------------------------------------------------------------------
// Fused kernel, low-pressure version: per block (k-half by, row-pair bx),
// loop c in 4 chunks of 32:
//   stage: load x -> Winograd input transform -> pack bf16 pairs -> LDS
//          (single 64 KB buffer, fused pass, ~48 transient VGPRs)
//   mfma : 16 ad x 2 MFMA(32x32x16), inverse transform folded into 4 Y accs.
// Block 512 thr (8 waves: 2 n-rows x 4 k-tiles). LDS 64 KB -> 2 blocks/CU.
// __launch_bounds__(512,4) pins VGPR <= 128 (round-1 spilled ~1 GB scratch).
// ---------------------------------------------------------------------------
__global__ __launch_bounds__(512, 4) void wino_fused(
        const float* __restrict__ x, const unsigned short* __restrict__ Up,
        const float* __restrict__ bias, float* __restrict__ out)
{
    __shared__ unsigned short Vs[16*4*64*8];   // [ad][cg][n][j] bf16 = 64 KB

    const bf16x8* U8 = (const bf16x8*)Up;
    const int t  = threadIdx.x;
    const int by = blockIdx.x;      // 0..1   k-split (fast axis)
    const int bx = blockIdx.y;      // 0..495 row-pair

    // ---- stage mapping: t = [cgb][rsel][qh][l4][jp] ----
    const int jp   = t & 3;          // c-pair within octet (4B LDS stride)
    const int l4   = (t >> 2) & 15;
    const int qh   = (t >> 6) & 1;
    const int rsel = (t >> 7) & 1;
    const int cgb  = (t >> 8) & 1;
    const int sq   = qh * 16 + l4;           // 0..31
    const int srow = bx * 2 + rsel;          // = b*31 + p
    const int sb   = srow / 31, sp = srow % 31;
    const int nloc_s = rsel * 32 + sq;
    const bool valid = (sq < 31);
    const float* xb = x + (((size_t)sb * 128) * 64 + 2 * sp) * 64 + 2 * sq;  // + c*4096

    // ---- mfma mapping ----
    const int lane = t & 63, wave = t >> 6;
    const int l31 = lane & 31, q2 = lane >> 5;
    const int wn = wave & 1, wk = wave >> 1;        // 2 n-rows x 4 k-tiles
    const int row = bx * 2 + wn;
    const int k0  = by * 128 + wk * 32;
    const int bOff = q2 * 256 + k0 + l31;
    const int aOff = wn * 32 + l31;

    f32x16 Y00, Y01, Y10, Y11;
    #pragma unroll
    for (int z = 0; z < 16; ++z) { Y00[z]=0.f; Y01[z]=0.f; Y10[z]=0.f; Y11[z]=0.f; }

    for (int chunk = 0; chunk < 4; ++chunk) {
        // ---------------- stage phase (load + transform + pack + LDS write) ----
        {
            unsigned* dst = (unsigned*)Vs;
            #pragma unroll
            for (int u = 0; u < 2; ++u) {
                unsigned pk[4][4];
                #pragma unroll
                for (int ch = 0; ch < 2; ++ch) {
                    const int c = chunk*32 + (u*2 + cgb)*8 + jp*2 + ch;
                    const float* p = xb + (size_t)c * 4096;
                    float dd[4][4];
                    #pragma unroll
                    for (int i = 0; i < 4; ++i) {
                        if (valid) {
                            float2 u0 = *(const float2*)(p + i*64);
                            float2 u1 = *(const float2*)(p + i*64 + 2);
                            dd[i][0]=u0.x; dd[i][1]=u0.y; dd[i][2]=u1.x; dd[i][3]=u1.y;
                        } else {
                            dd[i][0]=0.f; dd[i][1]=0.f; dd[i][2]=0.f; dd[i][3]=0.f;
                        }
                    }
                    float s[4][4];
                    #pragma unroll
                    for (int jj = 0; jj < 4; ++jj) {
                        s[0][jj] = dd[0][jj] - dd[2][jj];
                        s[1][jj] = dd[1][jj] + dd[2][jj];
                        s[2][jj] = dd[2][jj] - dd[1][jj];
                        s[3][jj] = dd[1][jj] - dd[3][jj];
                    }
                    #pragma unroll
                    for (int a = 0; a < 4; ++a) {
                        float v0 = s[a][0] - s[a][2];
                        float v1 = s[a][1] + s[a][2];
                        float v2 = s[a][2] - s[a][1];
                        float v3 = s[a][1] - s[a][3];
                        if (ch == 0) {
                            pk[a][0] = f2bf(v0);
                            pk[a][1] = f2bf(v1);
                            pk[a][2] = f2bf(v2);
                            pk[a][3] = f2bf(v3);
                        } else {
                            pk[a][0] |= (unsigned)f2bf(v0) << 16;
                            pk[a][1] |= (unsigned)f2bf(v1) << 16;
                            pk[a][2] |= (unsigned)f2bf(v2) << 16;
                            pk[a][3] |= (unsigned)f2bf(v3) << 16;
                        }
                    }
                }
                const int cg2  = u*2 + cgb;
                const int base = cg2*256 + nloc_s*4 + jp;
                #pragma unroll
                for (int a = 0; a < 4; ++a)
                    #pragma unroll
                    for (int d = 0; d < 4; ++d)
                        dst[(a*4 + d)*1024 + base] = pk[a][d];
            }
        }
        __syncthreads();

        // ---------------- mfma phase -----------------------------------------
        const bf16x8* va = (const bf16x8*)Vs;
        __builtin_amdgcn_s_setprio(1);
        #pragma unroll
        for (int ad = 0; ad < 16; ++ad) {
            f32x16 m;
            #pragma unroll
            for (int z = 0; z < 16; ++z) m[z] = 0.f;
            #pragma unroll
            for (int cb = 0; cb < 2; ++cb) {
                bf16x8 av = va[(ad*4 + cb*2 + q2)*64 + aOff];
                bf16x8 bv = U8[(size_t)(ad*16 + chunk*4 + cb*2)*256 + bOff];
                m = __builtin_amdgcn_mfma_f32_32x32x16_bf16(av, bv, m, 0, 0, 0);
            }
            const int a_i = ad >> 2, d_i = ad & 3;
            constexpr float A0[4] = {1.f, 1.f,  1.f,  0.f};
            constexpr float A1[4] = {0.f, 1.f, -1.f, -1.f};
            const float w00 = A0[a_i]*A0[d_i], w01 = A0[a_i]*A1[d_i];
            const float w10 = A1[a_i]*A0[d_i], w11 = A1[a_i]*A1[d_i];
            if (w00 != 0.f) Y00 += w00 * m;       // constant-folded -> add/sub
            if (w01 != 0.f) Y01 += w01 * m;
            if (w10 != 0.f) Y10 += w10 * m;
            if (w11 != 0.f) Y11 += w11 * m;
        }
        __builtin_amdgcn_s_setprio(0);
        __syncthreads();
    }

    // Epilogue: lane owns k-plane k0+l31; C/D row r -> q = (r&3)+8*(r>>2)+4*q2
    int b = row / 31, p = row % 31;
    int k = k0 + l31;
    float bvs = bias[k];
    float* op = out + (size_t)(b*256 + k) * 62 * 62;
    #pragma unroll
    for (int r = 0; r < 16; ++r) {
        int q = (r & 3) + 8*(r >> 2) + 4*q2;
        if (q < 31) {
            *(float2*)(op + (2*p+0)*62 + 2*q) = make_float2(Y00[r] + bvs, Y01[r] + bvs);
            *(float2*)(op + (2*p+1)*62 + 2*q) = make_float2(Y10[r] + bvs, Y11[r] + bvs);
        }
    }
}

// ---------------------------------------------------------------------------
extern "C" void kernel_launch(void* const* d_in, const int* in_sizes, int n_in,
                              void* d_out, int out_size, void* d_ws, size_t ws_size,
                              hipStream_t stream) {
    const float* x    = (const float*)d_in[0];
    const float* w    = (const float*)d_in[1];
    const float* bias = (const float*)d_in[2];
    float* out = (float*)d_out;

    unsigned short* Up = (unsigned short*)d_ws;   // 16*16*256*8 bf16 = 1 MB

    wino_wtrans<<<dim3(256),    dim3(128), 0, stream>>>(w, Up);
    wino_fused <<<dim3(2, 496), dim3(512), 0, stream>>>(x, Up, bias, out);
}

// Round 5
// 276.762 us; speedup vs baseline: 2.8739x; 1.0036x over previous
//
#include <hip/hip_runtime.h>

typedef __bf16  bf16x8 __attribute__((ext_vector_type(8)));
typedef float   f32x16 __attribute__((ext_vector_type(16)));

__device__ __forceinline__ unsigned short f2bf(float f) {
    union { float f; unsigned int u; } v; v.f = f;
    unsigned int r = (v.u + 0x7fffu + ((v.u >> 16) & 1u)) >> 16;
    return (unsigned short)r;
}

__device__ __forceinline__ bf16x8 neg8(bf16x8 v) {
    union { bf16x8 b; unsigned u[4]; } t; t.b = v;
    t.u[0] ^= 0x80008000u; t.u[1] ^= 0x80008000u;
    t.u[2] ^= 0x80008000u; t.u[3] ^= 0x80008000u;
    return t.b;
}

// ---------------------------------------------------------------------------
// Kernel A (verified R2 version, untouched): weight transform U = G g G^T,
// bf16 in MFMA B-fragment order: Up[((ad*16 + cg)*256 + k)*8 + j], c = cg*8+j
// ---------------------------------------------------------------------------
__global__ void wino_wtrans(const float* __restrict__ w, unsigned short* __restrict__ Up) {
    int k = blockIdx.x;        // 0..255
    int c = threadIdx.x;       // 0..127
    const float* g = w + (k * 128 + c) * 9;
    float g00=g[0],g01=g[1],g02=g[2],g10=g[3],g11=g[4],g12=g[5],g20=g[6],g21=g[7],g22=g[8];
    float T[4][3];
    T[0][0]=g00;                    T[0][1]=g01;                    T[0][2]=g02;
    T[1][0]=0.5f*(g00+g10+g20);     T[1][1]=0.5f*(g01+g11+g21);     T[1][2]=0.5f*(g02+g12+g22);
    T[2][0]=0.5f*(g00-g10+g20);     T[2][1]=0.5f*(g01-g11+g21);     T[2][2]=0.5f*(g02-g12+g22);
    T[3][0]=g20;                    T[3][1]=g21;                    T[3][2]=g22;
    int cg = c >> 3, j = c & 7;
    #pragma unroll
    for (int a = 0; a < 4; ++a) {
        float u0 = T[a][0];
        float u1 = 0.5f*(T[a][0]+T[a][1]+T[a][2]);
        float u2 = 0.5f*(T[a][0]-T[a][1]+T[a][2]);
        float u3 = T[a][2];
        float uu[4] = {u0,u1,u2,u3};
        #pragma unroll
        for (int d = 0; d < 4; ++d) {
            Up[(((size_t)((a*4+d)*16 + cg))*256 + k)*8 + j] = f2bf(uu[d]);
        }
    }
}

// ---------------------------------------------------------------------------
// Fused kernel = verified R2 structure with ONE change: the inverse-transform
// fold is moved INTO the MFMA accumulator chain. At entries are {0,+1,-1}, so
// each (ad,cb) MFMA is issued directly into the Y accumulators it feeds, with
// a sign-flipped A-fragment (v_xor of sign bits) for negative weights.
// Removes per-ad zero-init (256 v_mov) + fold adds (~576 f32x16) per chunk.
// Everything else (grid, LDS, stage, epilogue) identical to the passing R2.
// ---------------------------------------------------------------------------
__global__ __launch_bounds__(512, 4) void wino_fused(
        const float* __restrict__ x, const unsigned short* __restrict__ Up,
        const float* __restrict__ bias, float* __restrict__ out)
{
    __shared__ unsigned short Vs[16*4*64*8];   // [ad][cg][n][j] bf16 = 64 KB

    const bf16x8* U8 = (const bf16x8*)Up;
    const int t  = threadIdx.x;
    const int by = blockIdx.x;      // 0..1   k-split (fast axis)
    const int bx = blockIdx.y;      // 0..495 row-pair

    // ---- stage mapping: t = [cgb][rsel][qh][l4][jp] ----
    const int jp   = t & 3;          // c-pair within octet (4B LDS stride)
    const int l4   = (t >> 2) & 15;
    const int qh   = (t >> 6) & 1;
    const int rsel = (t >> 7) & 1;
    const int cgb  = (t >> 8) & 1;
    const int sq   = qh * 16 + l4;           // 0..31
    const int srow = bx * 2 + rsel;          // = b*31 + p
    const int sb   = srow / 31, sp = srow % 31;
    const int nloc_s = rsel * 32 + sq;
    const bool valid = (sq < 31);
    const float* xb = x + (((size_t)sb * 128) * 64 + 2 * sp) * 64 + 2 * sq;  // + c*4096

    // ---- mfma mapping ----
    const int lane = t & 63, wave = t >> 6;
    const int l31 = lane & 31, q2 = lane >> 5;
    const int wn = wave & 1, wk = wave >> 1;        // 2 n-rows x 4 k-tiles
    const int row = bx * 2 + wn;
    const int k0  = by * 128 + wk * 32;
    const int bOff = q2 * 256 + k0 + l31;
    const int aOff = wn * 32 + l31;

    f32x16 Y00, Y01, Y10, Y11;
    #pragma unroll
    for (int z = 0; z < 16; ++z) { Y00[z]=0.f; Y01[z]=0.f; Y10[z]=0.f; Y11[z]=0.f; }

    for (int chunk = 0; chunk < 4; ++chunk) {
        // ---------------- stage phase (load + transform + pack + LDS write) ----
        {
            unsigned* dst = (unsigned*)Vs;
            #pragma unroll
            for (int u = 0; u < 2; ++u) {
                unsigned pk[4][4];
                #pragma unroll
                for (int ch = 0; ch < 2; ++ch) {
                    const int c = chunk*32 + (u*2 + cgb)*8 + jp*2 + ch;
                    const float* p = xb + (size_t)c * 4096;
                    float dd[4][4];
                    #pragma unroll
                    for (int i = 0; i < 4; ++i) {
                        if (valid) {
                            float2 u0 = *(const float2*)(p + i*64);
                            float2 u1 = *(const float2*)(p + i*64 + 2);
                            dd[i][0]=u0.x; dd[i][1]=u0.y; dd[i][2]=u1.x; dd[i][3]=u1.y;
                        } else {
                            dd[i][0]=0.f; dd[i][1]=0.f; dd[i][2]=0.f; dd[i][3]=0.f;
                        }
                    }
                    float s[4][4];
                    #pragma unroll
                    for (int jj = 0; jj < 4; ++jj) {
                        s[0][jj] = dd[0][jj] - dd[2][jj];
                        s[1][jj] = dd[1][jj] + dd[2][jj];
                        s[2][jj] = dd[2][jj] - dd[1][jj];
                        s[3][jj] = dd[1][jj] - dd[3][jj];
                    }
                    #pragma unroll
                    for (int a = 0; a < 4; ++a) {
                        float v0 = s[a][0] - s[a][2];
                        float v1 = s[a][1] + s[a][2];
                        float v2 = s[a][2] - s[a][1];
                        float v3 = s[a][1] - s[a][3];
                        if (ch == 0) {
                            pk[a][0] = f2bf(v0);
                            pk[a][1] = f2bf(v1);
                            pk[a][2] = f2bf(v2);
                            pk[a][3] = f2bf(v3);
                        } else {
                            pk[a][0] |= (unsigned)f2bf(v0) << 16;
                            pk[a][1] |= (unsigned)f2bf(v1) << 16;
                            pk[a][2] |= (unsigned)f2bf(v2) << 16;
                            pk[a][3] |= (unsigned)f2bf(v3) << 16;
                        }
                    }
                }
                const int cg2  = u*2 + cgb;
                const int base = cg2*256 + nloc_s*4 + jp;
                #pragma unroll
                for (int a = 0; a < 4; ++a)
                    #pragma unroll
                    for (int d = 0; d < 4; ++d)
                        dst[(a*4 + d)*1024 + base] = pk[a][d];
            }
        }
        __syncthreads();

        // ---------------- mfma phase: fold chained into accumulators ---------
        // Y00 gets +m[a][d] for a<=2,d<=2;  Y01 gets A1[d]*m for a<=2,d>=1;
        // Y10 gets A1[a]*m for a>=1,d<=2;   Y11 gets A1[a]*A1[d]*m for a,d>=1;
        // A1 = {0,+1,-1,-1}  -> sign handled by negating the A fragment.
        const bf16x8* va = (const bf16x8*)Vs;
        __builtin_amdgcn_s_setprio(1);
        #pragma unroll
        for (int ad = 0; ad < 16; ++ad) {
            const int A_ = ad >> 2, D_ = ad & 3;
            const bool t00 = (A_ <= 2) && (D_ <= 2);
            const bool t01 = (A_ <= 2) && (D_ >= 1);
            const bool t10 = (A_ >= 1) && (D_ <= 2);
            const bool t11 = (A_ >= 1) && (D_ >= 1);
            const bool sd = (D_ >= 2), sa = (A_ >= 2);
            const bool needn = (t01 && sd) || (t10 && sa) || (t11 && (sa != sd));
            #pragma unroll
            for (int cb = 0; cb < 2; ++cb) {
                bf16x8 av = va[(ad*4 + cb*2 + q2)*64 + aOff];
                bf16x8 bv = U8[(size_t)(ad*16 + chunk*4 + cb*2)*256 + bOff];
                bf16x8 nv = needn ? neg8(av) : av;
                if (t00) Y00 = __builtin_amdgcn_mfma_f32_32x32x16_bf16(av, bv, Y00, 0, 0, 0);
                if (t01) Y01 = __builtin_amdgcn_mfma_f32_32x32x16_bf16(sd ? nv : av, bv, Y01, 0, 0, 0);
                if (t10) Y10 = __builtin_amdgcn_mfma_f32_32x32x16_bf16(sa ? nv : av, bv, Y10, 0, 0, 0);
                if (t11) Y11 = __builtin_amdgcn_mfma_f32_32x32x16_bf16((sa != sd) ? nv : av, bv, Y11, 0, 0, 0);
            }
        }
        __builtin_amdgcn_s_setprio(0);
        __syncthreads();
    }

    // Epilogue: lane owns k-plane k0+l31; C/D row r -> q = (r&3)+8*(r>>2)+4*q2
    int b = row / 31, p = row % 31;
    int k = k0 + l31;
    float bvs = bias[k];
    float* op = out + (size_t)(b*256 + k) * 62 * 62;
    #pragma unroll
    for (int r = 0; r < 16; ++r) {
        int q = (r & 3) + 8*(r >> 2) + 4*q2;
        if (q < 31) {
            *(float2*)(op + (2*p+0)*62 + 2*q) = make_float2(Y00[r] + bvs, Y01[r] + bvs);
            *(float2*)(op + (2*p+1)*62 + 2*q) = make_float2(Y10[r] + bvs, Y11[r] + bvs);
        }
    }
}

// ---------------------------------------------------------------------------
extern "C" void kernel_launch(void* const* d_in, const int* in_sizes, int n_in,
                              void* d_out, int out_size, void* d_ws, size_t ws_size,
                              hipStream_t stream) {
    const float* x    = (const float*)d_in[0];
    const float* w    = (const float*)d_in[1];
    const float* bias = (const float*)d_in[2];
    float* out = (float*)d_out;

    unsigned short* Up = (unsigned short*)d_ws;   // 16*16*256*8 bf16 = 1 MB

    wino_wtrans<<<dim3(256),    dim3(128), 0, stream>>>(w, Up);
    wino_fused <<<dim3(2, 496), dim3(512), 0, stream>>>(x, Up, bias, out);
}